// Round 11
// baseline (472.115 us; speedup 1.0000x reference)
//
#include <hip/hip_runtime.h>
#include <hip/hip_bf16.h>
#include <math.h>

// Problem dims
#define CC 128          // C
#define DI 256          // D_INNER
#define SSEQ 256        // B*N sequences
#define ROWS 65536      // SSEQ*TT

typedef __hip_bfloat16 bf16;
typedef __attribute__((ext_vector_type(8))) short short8;   // 8 bf16 (4 VGPRs) MFMA A/B frag
typedef __attribute__((ext_vector_type(4))) float float4v;  // MFMA C/D frag
typedef __attribute__((ext_vector_type(2))) float f32x2;    // packed fp32 (v_pk_*)

__device__ __forceinline__ float to_f(float v) { return v; }
__device__ __forceinline__ float to_f(bf16 v)  { return __bfloat162float(v); }
__device__ __forceinline__ bf16  f2b(float v)  { return __float2bfloat16(v); }
__device__ __forceinline__ float bf2f_bits(short v) {
    union { unsigned u; float f; } c; c.u = ((unsigned)(unsigned short)v) << 16; return c.f;
}
__device__ __forceinline__ f32x2 mk2(float a, float b) { f32x2 r; r.x = a; r.y = b; return r; }
__device__ __forceinline__ f32x2 fma2(f32x2 a, f32x2 b, f32x2 c) { return a * b + c; }

__device__ __forceinline__ float wave_sum(float v) {
    #pragma unroll
    for (int o = 1; o < 64; o <<= 1) v += __shfl_xor(v, o, 64);
    return v;
}
__device__ __forceinline__ float silu_f(float x) {
    return x * __builtin_amdgcn_rcpf(1.f + __expf(-x));
}
__device__ __forceinline__ float gelu_f(float x) { return 0.5f * x * (1.f + erff(x * 0.70710678118654752f)); }
__device__ __forceinline__ float softplus_f(float x) {
    return (x > 20.f) ? x : __logf(1.f + __expf(x));
}

// ======== Fused LN1 + W_in GEMM: XZ[64 rows][512] per block ========
// Replaces ln1_kernel + the 64x64-tile W_in GEMM.  Phase 0: LN1 in-register
// (4 lanes/row, 2 shuffles — mlp_fused pattern) -> As staged ONCE.  Then 8
// N-tiles, each staging B full-K (one barrier pair) + 16 MFMA/wave.  Barriers
// per A-tile 64->16, A staged 1x instead of 8x, LN1OUT 48MB round-trip gone.
// Bs/As row stride 136 bf16 = 68 dwords = 4 mod 32 -> 2-way (free, G4).
__global__ __launch_bounds__(256) void ln1_win_kernel(
        const float* __restrict__ x,
        const float* __restrict__ g, const float* __restrict__ b,
        const float* __restrict__ Win,      // [512][128] fp32
        bf16* __restrict__ XZ) {            // [ROWS][512] bf16
    __shared__ bf16 As[64][136];
    __shared__ bf16 Bs[64][136];
    int tid = threadIdx.x;
    int m0 = blockIdx.x * 64;
    int wv = tid >> 6, lane = tid & 63;
    int lrow = lane & 15, quad = lane >> 4;
    int lk = quad * 8;

    // ---- Phase 0: LN1 on 64 rows of x (transposed gather) -> As bf16 ----
    {
        int m = tid >> 2, part = tid & 3;      // 4 threads/row, 32 floats each
        int r = m0 + m;
        int s = r >> 8, t = r & 255;
        int bb = s >> 6, nn = s & 63;
        const float* src = x + (((size_t)(bb * 256 + t)) * 64 + nn) * CC + part * 32;
        float v[32];
        #pragma unroll
        for (int i = 0; i < 8; i++) {
            float4 q = ((const float4*)src)[i];
            v[i * 4 + 0] = q.x; v[i * 4 + 1] = q.y;
            v[i * 4 + 2] = q.z; v[i * 4 + 3] = q.w;
        }
        float s1 = 0.f, s2 = 0.f;
        #pragma unroll
        for (int i = 0; i < 32; i++) { s1 += v[i]; s2 += v[i] * v[i]; }
        s1 += __shfl_xor(s1, 1, 64); s2 += __shfl_xor(s2, 1, 64);
        s1 += __shfl_xor(s1, 2, 64); s2 += __shfl_xor(s2, 2, 64);
        float mean = s1 * (1.f / 128.f);
        float var = s2 * (1.f / 128.f) - mean * mean;
        float rstd = rsqrtf(var + 1e-5f);
        #pragma unroll
        for (int i8 = 0; i8 < 4; i8++) {
            bf16 tmp[8];
            #pragma unroll
            for (int j = 0; j < 8; j++) {
                int col = part * 32 + i8 * 8 + j;
                tmp[j] = f2b((v[i8 * 8 + j] - mean) * rstd * g[col] + b[col]);
            }
            *(uint4*)&As[m][part * 32 + i8 * 8] = *(uint4*)tmp;
        }
    }
    __syncthreads();

    // ---- N-loop: 8 tiles of 64 output channels; B staged full-K per tile ----
    #pragma unroll 1
    for (int nt = 0; nt < 8; nt++) {
        {
            int n = tid >> 2, part = tid & 3;
            const float* srcB = Win + ((size_t)(nt * 64 + n)) * CC + part * 32;
            #pragma unroll
            for (int i8 = 0; i8 < 4; i8++) {
                bf16 tmp[8];
                #pragma unroll
                for (int j = 0; j < 8; j++) tmp[j] = f2b(srcB[i8 * 8 + j]);
                *(uint4*)&Bs[n][part * 32 + i8 * 8] = *(uint4*)tmp;
            }
        }
        __syncthreads();
        float4v acc[4] = {};
        #pragma unroll
        for (int kt = 0; kt < 4; kt++) {
            short8 a = *(const short8*)&As[wv * 16 + lrow][kt * 32 + lk];
            #pragma unroll
            for (int jt = 0; jt < 4; jt++) {
                short8 bfr = *(const short8*)&Bs[jt * 16 + lrow][kt * 32 + lk];
                acc[jt] = __builtin_amdgcn_mfma_f32_16x16x32_bf16(a, bfr, acc[jt], 0, 0, 0);
            }
        }
        #pragma unroll
        for (int jt = 0; jt < 4; jt++) {
            int col = nt * 64 + jt * 16 + lrow;
            #pragma unroll
            for (int r = 0; r < 4; r++) {
                int row = m0 + wv * 16 + quad * 4 + r;
                XZ[(size_t)row * 512 + col] = f2b(acc[jt][r]);
            }
        }
        __syncthreads();   // protect Bs before next tile's staging
    }
}

// ======== MFMA W_out GEMM (64x128 tile), A = (YF+YB)*silu(z), fused LN2 + residual ========
__global__ __launch_bounds__(256) void mfma_ln2res_kernel(const bf16* __restrict__ YF,
                                                          const bf16* __restrict__ YB,
                                                          const bf16* __restrict__ xz,
                                                          const float* __restrict__ Wout,
                                                          const float* __restrict__ g,
                                                          const float* __restrict__ b,
                                                          const float* __restrict__ x,
                                                          float* __restrict__ out) {
    __shared__ bf16 As[64][40];
    __shared__ bf16 Bs[128][40];
    int tid = threadIdx.x;
    int m0 = blockIdx.x * 64;
    int wv = tid >> 6, lane = tid & 63;
    int lrow = lane & 15, quad = lane >> 4;
    int lk = quad * 8;
    float4v acc[8] = {};
    #pragma unroll
    for (int kt = 0; kt < 8; kt++) {          // K = 256
        int k0 = kt * 32;
        {
            int m = tid >> 2, part = tid & 3;
            size_t off = (size_t)(m0 + m) * 256 + k0 + part * 8;
            short8 vf = *(const short8*)(YF + off);
            short8 vb = *(const short8*)(YB + off);
            short8 vz = *(const short8*)(xz + (size_t)(m0 + m) * 512 + 256 + k0 + part * 8);
            bf16 tmp[8];
            #pragma unroll
            for (int j = 0; j < 8; j++)
                tmp[j] = f2b((bf2f_bits(vf[j]) + bf2f_bits(vb[j])) * silu_f(bf2f_bits(vz[j])));
            *(uint4*)&As[m][part * 8] = *(uint4*)tmp;
        }
        #pragma unroll
        for (int it = 0; it < 2; it++) {
            int idx = tid + it * 256;
            int n = idx >> 2, part = idx & 3;
            const float* src = Wout + (size_t)n * 256 + k0 + part * 8;
            bf16 tmp[8];
            #pragma unroll
            for (int j = 0; j < 8; j++) tmp[j] = f2b(src[j]);
            *(uint4*)&Bs[n][part * 8] = *(uint4*)tmp;
        }
        __syncthreads();
        short8 a = *(const short8*)&As[wv * 16 + lrow][lk];
        #pragma unroll
        for (int jt = 0; jt < 8; jt++) {
            short8 bfr = *(const short8*)&Bs[jt * 16 + lrow][lk];
            acc[jt] = __builtin_amdgcn_mfma_f32_16x16x32_bf16(a, bfr, acc[jt], 0, 0, 0);
        }
        __syncthreads();
    }
    #pragma unroll
    for (int r = 0; r < 4; r++) {
        float ps = 0.f, ps2 = 0.f;
        #pragma unroll
        for (int jt = 0; jt < 8; jt++) { float v = acc[jt][r]; ps += v; ps2 += v * v; }
        #pragma unroll
        for (int o = 1; o < 16; o <<= 1) {
            ps  += __shfl_xor(ps, o, 64);
            ps2 += __shfl_xor(ps2, o, 64);
        }
        float m = ps * (1.f / 128.f);
        float var = ps2 * (1.f / 128.f) - m * m;
        float rstd = rsqrtf(var + 1e-5f);
        int row = m0 + wv * 16 + quad * 4 + r;
        int s = row >> 8, t = row & 255;
        int bb = s >> 6, n = s & 63;
        size_t xbase = (((size_t)(bb * 256 + t)) * 64 + n) * CC;
        #pragma unroll
        for (int jt = 0; jt < 8; jt++) {
            int col = jt * 16 + lrow;
            out[xbase + col] = (acc[jt][r] - m) * rstd * g[col] + b[col] + x[xbase + col];
        }
    }
}

// ======== MFMA xdbl GEMM with fused causal conv + SiLU A-staging ========
template <int DIR>
__global__ __launch_bounds__(256) void mfma_conv_kernel(const bf16* __restrict__ xz,
                                                        const float* __restrict__ cw,
                                                        const float* __restrict__ cb,
                                                        const float* __restrict__ Wx,
                                                        bf16* __restrict__ C,
                                                        bf16* __restrict__ U) {
    __shared__ bf16 As[64][40];
    __shared__ bf16 Bs[48][40];
    int tid = threadIdx.x;
    int s = blockIdx.x >> 2;
    int t0 = (blockIdx.x & 3) * 64;
    int wv = tid >> 6, lane = tid & 63;
    int lrow = lane & 15, quad = lane >> 4;
    int lk = quad * 8;
    float4v acc[3] = {};
    #pragma unroll
    for (int kt = 0; kt < 8; kt++) {          // K = 256 channels
        int k0 = kt * 32;
        {
            int m = tid >> 2, part = tid & 3;
            int t = t0 + m;
            int dbase = k0 + part * 8;
            float a[8];
            float4 w4[8];
            #pragma unroll
            for (int i = 0; i < 8; i++) {
                a[i]  = cb[dbase + i];
                w4[i] = ((const float4*)cw)[dbase + i];   // cw[d][0..3]
            }
            #pragma unroll
            for (int j = 0; j < 4; j++) {
                int tj = t - 3 + j;
                if (tj >= 0) {
                    int src = DIR ? (255 - tj) : tj;
                    uint4 v = *(const uint4*)(xz + (size_t)(s * 256 + src) * 512 + dbase);
                    short8 sv = *(short8*)&v;
                    #pragma unroll
                    for (int i = 0; i < 8; i++) {
                        float w = (j == 0) ? w4[i].x : (j == 1) ? w4[i].y : (j == 2) ? w4[i].z : w4[i].w;
                        a[i] += w * bf2f_bits(sv[i]);
                    }
                }
            }
            bf16 tmp[8];
            #pragma unroll
            for (int i = 0; i < 8; i++) tmp[i] = f2b(silu_f(a[i]));
            *(uint4*)&As[m][part * 8] = *(uint4*)tmp;
            int tu = DIR ? (255 - t) : t;
            *(uint4*)&U[((size_t)(s * 256 + tu)) * 256 + dbase] = *(uint4*)tmp;
        }
        {
            int n = tid >> 2, part = tid & 3;
            if (n < 48) {
                bf16 tmp[8];
                #pragma unroll
                for (int j = 0; j < 8; j++)
                    tmp[j] = (n < 40) ? f2b(Wx[(size_t)n * 256 + k0 + part * 8 + j]) : f2b(0.f);
                *(uint4*)&Bs[n][part * 8] = *(uint4*)tmp;
            }
        }
        __syncthreads();
        short8 a = *(const short8*)&As[wv * 16 + lrow][lk];
        #pragma unroll
        for (int jt = 0; jt < 3; jt++) {
            short8 bfr = *(const short8*)&Bs[jt * 16 + lrow][lk];
            acc[jt] = __builtin_amdgcn_mfma_f32_16x16x32_bf16(a, bfr, acc[jt], 0, 0, 0);
        }
        __syncthreads();
    }
    #pragma unroll
    for (int jt = 0; jt < 3; jt++) {
        int col = jt * 16 + lrow;
        if (col < 40) {
            #pragma unroll
            for (int r = 0; r < 4; r++) {
                int row = t0 + wv * 16 + quad * 4 + r;
                C[(size_t)(s * 256 + row) * 40 + col] = f2b(acc[jt][r]);
            }
        }
    }
}

// ---------------- Selective scan v10 (unchanged from R8: 102us) ----------------

#define LOADROW(R, T) do {                                                  \
    const float4* rp_ = (const float4*)(rows + (T) * 40);                   \
    R##0 = rp_[0]; R##1 = rp_[1]; R##2 = rp_[2]; R##3 = rp_[3];             \
    R##4 = rp_[4]; R##5 = rp_[5]; R##6 = rp_[6]; R##7 = rp_[7];             \
    R##8 = rp_[8]; R##9 = rp_[9];                                           \
} while (0)

#define SCAN_STEP(JJ, R) do {                                               \
    float u_ = to_f(ub[(JJ) * 256 + d]);                                    \
    f32x2 acc2 = mk2((R##0).x, (R##0).y) * wdt01;                           \
    acc2 = fma2(mk2((R##0).z, (R##0).w), wdt23, acc2);                      \
    acc2 = fma2(mk2((R##1).x, (R##1).y), wdt45, acc2);                      \
    acc2 = fma2(mk2((R##1).z, (R##1).w), wdt67, acc2);                      \
    float dtr_ = bd + acc2.x + acc2.y;                                      \
    float dt_ = softplus_f(dtr_);                                           \
    float du_ = dt_ * u_;                                                   \
    float d1 = __expf(dt_ * A0);                                            \
    float d2v = d1 * d1;                                                    \
    f32x2 pw0 = mk2(d1, d2v);                                               \
    f32x2 dd2 = mk2(d2v, d2v);                                              \
    f32x2 pw1 = pw0 * dd2, pw2 = pw1 * dd2, pw3 = pw2 * dd2;                \
    f32x2 dd8 = mk2(pw3.y, pw3.y);                                          \
    f32x2 pw4 = pw0 * dd8, pw5 = pw1 * dd8, pw6 = pw2 * dd8, pw7 = pw3 * dd8; \
    f32x2 du2 = mk2(du_, du_);                                              \
    hp0 = fma2(pw0, hp0, du2 * mk2((R##2).x, (R##2).y));                    \
    hp1 = fma2(pw1, hp1, du2 * mk2((R##2).z, (R##2).w));                    \
    hp2 = fma2(pw2, hp2, du2 * mk2((R##3).x, (R##3).y));                    \
    hp3 = fma2(pw3, hp3, du2 * mk2((R##3).z, (R##3).w));                    \
    hp4 = fma2(pw4, hp4, du2 * mk2((R##4).x, (R##4).y));                    \
    hp5 = fma2(pw5, hp5, du2 * mk2((R##4).z, (R##4).w));                    \
    hp6 = fma2(pw6, hp6, du2 * mk2((R##5).x, (R##5).y));                    \
    hp7 = fma2(pw7, hp7, du2 * mk2((R##5).z, (R##5).w));                    \
    f32x2 ya = hp0 * mk2((R##6).x, (R##6).y);                               \
    f32x2 yb2 = hp1 * mk2((R##6).z, (R##6).w);                              \
    ya = fma2(hp2, mk2((R##7).x, (R##7).y), ya);                            \
    yb2 = fma2(hp3, mk2((R##7).z, (R##7).w), yb2);                          \
    ya = fma2(hp4, mk2((R##8).x, (R##8).y), ya);                            \
    yb2 = fma2(hp5, mk2((R##8).z, (R##8).w), yb2);                          \
    ya = fma2(hp6, mk2((R##9).x, (R##9).y), ya);                            \
    yb2 = fma2(hp7, mk2((R##9).z, (R##9).w), yb2);                          \
    f32x2 ys = ya + yb2;                                                    \
    float yv_ = ys.x + ys.y + u_ * Dd;                                      \
    *yp = f2b(yv_); yp += ystep;                                            \
} while (0)

// stage one 32-step u chunk (16 KB) into u_lds[buf]; fully coalesced
#define STAGE_U(BUF, C0) do {                                               \
    _Pragma("unroll")                                                       \
    for (int q_ = 0; q_ < 4; q_++) {                                        \
        int flat_ = q_ * 256 + tid;                                         \
        int j_ = flat_ >> 5, w_ = flat_ & 31;                               \
        int t_ = (C0) + j_;                                                 \
        int grow_ = dir ? (255 - t_) : t_;                                  \
        ((uint4*)u_lds)[(BUF) * 1024 + flat_] =                             \
            *((const uint4*)(Y + ((size_t)(s * 256 + grow_)) * 256) + w_);  \
    }                                                                       \
} while (0)

__global__ __launch_bounds__(256, 2) void scan_kernel(
        const bf16* __restrict__ xdbl_f, const bf16* __restrict__ xdbl_b,
        const float* __restrict__ Wdt_f, const float* __restrict__ bdt_f,
        const float* __restrict__ Alog_f, const float* __restrict__ D_f,
        const float* __restrict__ Wdt_b, const float* __restrict__ bdt_b,
        const float* __restrict__ Alog_b, const float* __restrict__ D_b,
        bf16* __restrict__ YF, bf16* __restrict__ YB) {
    __shared__ float rows[256 * 40];     // 40 KB fp32
    __shared__ bf16  u_lds[2 * 8192];    // 32 KB: 2 x (32 steps x 256 ch)
    int tid = threadIdx.x;
    int dir = blockIdx.x >> 8;
    int s = blockIdx.x & 255;
    int d = tid;

    const bf16* xd = (dir ? xdbl_b : xdbl_f) + (size_t)s * 10240;
    #pragma unroll
    for (int i = 0; i < 5; i++) {
        int idx = i * 256 + tid;
        uint4 v = ((const uint4*)xd)[idx];
        short8 sv = *(short8*)&v;
        float f[8];
        #pragma unroll
        for (int j = 0; j < 8; j++) f[j] = bf2f_bits(sv[j]);
        *(float4*)&rows[idx * 8]     = *(float4*)&f[0];
        *(float4*)&rows[idx * 8 + 4] = *(float4*)&f[4];
    }

    const float* Alog = dir ? Alog_b : Alog_f;
    const float* Wdtp = dir ? Wdt_b  : Wdt_f;
    float Aarr[16];
    #pragma unroll
    for (int n = 0; n < 16; n++) Aarr[n] = -__expf(Alog[d * 16 + n]);
    f32x2 wdt01 = mk2(Wdtp[d * 8 + 0], Wdtp[d * 8 + 1]);
    f32x2 wdt23 = mk2(Wdtp[d * 8 + 2], Wdtp[d * 8 + 3]);
    f32x2 wdt45 = mk2(Wdtp[d * 8 + 4], Wdtp[d * 8 + 5]);
    f32x2 wdt67 = mk2(Wdtp[d * 8 + 6], Wdtp[d * 8 + 7]);
    float bd = dir ? bdt_b[d] : bdt_f[d];
    float Dd = dir ? D_b[d]   : D_f[d];
    bf16* Y = dir ? YB : YF;

    // Structure check: A[n] == (n+1)*A[0]
    float A0 = Aarr[0];
    int pw = 1;
    #pragma unroll
    for (int n = 1; n < 16; n++)
        pw &= (fabsf(Aarr[n] - (float)(n + 1) * A0) <= 1e-4f * fabsf(Aarr[n]) + 1e-6f) ? 1 : 0;
    pw = __all(pw);

    // stage u chunk 0
    STAGE_U(0, 0);
    __syncthreads();

    // y pointer walks the same buffer u was staged from (u already in LDS)
    bf16* yp = Y + ((size_t)(s * 256 + (dir ? 255 : 0))) * 256 + d;
    ptrdiff_t ystep = dir ? -256 : 256;

    if (pw) {
        f32x2 hp0 = {}, hp1 = {}, hp2 = {}, hp3 = {},
              hp4 = {}, hp5 = {}, hp6 = {}, hp7 = {};
        float4 ra0, ra1, ra2, ra3, ra4, ra5, ra6, ra7, ra8, ra9;
        float4 rb0, rb1, rb2, rb3, rb4, rb5, rb6, rb7, rb8, rb9;
        LOADROW(ra, 0);
        #pragma unroll 1
        for (int c = 0; c < 8; c++) {
            if (c + 1 < 8) STAGE_U((c + 1) & 1, (c + 1) * 32);
            const bf16* ub = u_lds + (c & 1) * 8192;
            int tc = c * 32;
            #pragma unroll 2
            for (int j = 0; j < 32; j += 2) {
                int t = tc + j;
                LOADROW(rb, t + 1);
                SCAN_STEP(j, ra);
                if (t + 2 < 256) LOADROW(ra, t + 2);
                SCAN_STEP(j + 1, rb);
            }
            __syncthreads();
        }
    } else {
        float h[16];
        #pragma unroll
        for (int n = 0; n < 16; n++) h[n] = 0.f;
        #pragma unroll 1
        for (int c = 0; c < 8; c++) {
            if (c + 1 < 8) STAGE_U((c + 1) & 1, (c + 1) * 32);
            const bf16* ub = u_lds + (c & 1) * 8192;
            int tc = c * 32;
            #pragma unroll 1
            for (int j = 0; j < 32; j++) {
                float u = to_f(ub[j * 256 + d]);
                const float* row = rows + (tc + j) * 40;
                float4 q0 = *(const float4*)(row);
                float4 q1 = *(const float4*)(row + 4);
                float dtr = bd;
                dtr += q0.x * wdt01.x + q0.y * wdt01.y + q0.z * wdt23.x + q0.w * wdt23.y;
                dtr += q1.x * wdt45.x + q1.y * wdt45.y + q1.z * wdt67.x + q1.w * wdt67.y;
                float dt = softplus_f(dtr);
                float du = dt * u, y = 0.f;
                #pragma unroll
                for (int n = 0; n < 16; n++) {
                    float dA = __expf(dt * Aarr[n]);
                    h[n] = dA * h[n] + du * row[8 + n];
                    y += h[n] * row[24 + n];
                }
                y += u * Dd;
                *yp = f2b(y); yp += ystep;
            }
            __syncthreads();
        }
    }
}

// ---------------- Weight pre-transpose: W1m/W2m fp32 k-major -> bf16 n-major ----------------
__global__ __launch_bounds__(256) void prep_w_kernel(const float* __restrict__ W1m,
                                                     const float* __restrict__ W2m,
                                                     bf16* __restrict__ W1T,
                                                     bf16* __restrict__ W2T) {
    int e = blockIdx.x * 256 + threadIdx.x;   // 0..32767
    {   // W1m [128][256] -> W1T [256][128]
        int k = e >> 8, n = e & 255;
        W1T[n * 128 + k] = f2b(W1m[k * 256 + n]);
    }
    {   // W2m [256][128] -> W2T [128][256]
        int k = e >> 7, n = e & 127;
        W2T[n * 256 + k] = f2b(W2m[k * 128 + n]);
    }
}

// ---------------- Fused MLP tail: LN3 + gelu(H@W1m+b1m)@W2m + b2m + residual ----------------
__global__ __launch_bounds__(256) void mlp_fused_kernel(
        float* __restrict__ out,
        const float* __restrict__ g3, const float* __restrict__ b3,
        const bf16* __restrict__ W1T, const float* __restrict__ b1m,
        const bf16* __restrict__ W2T, const float* __restrict__ b2m) {
    __shared__ bf16 As[64][136];   // LN3 rows (272B stride)
    __shared__ bf16 Hs[64][264];   // hidden   (528B stride)
    __shared__ bf16 Bs[256][40];   // weight k-tile (shared by both GEMMs)
    int tid = threadIdx.x;
    int m0 = blockIdx.x * 64;
    int wv = tid >> 6, lane = tid & 63;
    int lrow = lane & 15, quad = lane >> 4;
    int lk = quad * 8;

    // ---- Phase 0: LN3 on 64 rows -> As (bf16) ----
    {
        int m = tid >> 2, part = tid & 3;        // 4 threads/row, 32 floats each
        const float* src = out + (size_t)(m0 + m) * CC + part * 32;
        float v[32];
        #pragma unroll
        for (int i = 0; i < 8; i++) {
            float4 q = ((const float4*)src)[i];
            v[i * 4 + 0] = q.x; v[i * 4 + 1] = q.y;
            v[i * 4 + 2] = q.z; v[i * 4 + 3] = q.w;
        }
        float s1 = 0.f, s2 = 0.f;
        #pragma unroll
        for (int i = 0; i < 32; i++) { s1 += v[i]; s2 += v[i] * v[i]; }
        s1 += __shfl_xor(s1, 1, 64); s2 += __shfl_xor(s2, 1, 64);
        s1 += __shfl_xor(s1, 2, 64); s2 += __shfl_xor(s2, 2, 64);
        float mean = s1 * (1.f / 128.f);
        float var = s2 * (1.f / 128.f) - mean * mean;
        float rstd = rsqrtf(var + 1e-5f);
        #pragma unroll
        for (int i8 = 0; i8 < 4; i8++) {
            bf16 tmp[8];
            #pragma unroll
            for (int j = 0; j < 8; j++) {
                int col = part * 32 + i8 * 8 + j;
                tmp[j] = f2b((v[i8 * 8 + j] - mean) * rstd * g3[col] + b3[col]);
            }
            *(uint4*)&As[m][part * 32 + i8 * 8] = *(uint4*)tmp;
        }
    }
    __syncthreads();

    // ---- GEMM1: H = gelu(LN3 @ W1m + b1m), K=128, N=256 -> Hs ----
    {
        float4v acc1[16] = {};
        #pragma unroll
        for (int kt = 0; kt < 4; kt++) {
            int k0 = kt * 32;
            #pragma unroll
            for (int it = 0; it < 4; it++) {
                int idx = tid + it * 256;
                int n = idx >> 2, part = idx & 3;
                *(uint4*)&Bs[n][part * 8] =
                    *(const uint4*)(W1T + (size_t)n * 128 + k0 + part * 8);
            }
            __syncthreads();
            short8 a = *(const short8*)&As[wv * 16 + lrow][k0 + lk];
            #pragma unroll
            for (int jt = 0; jt < 16; jt++) {
                short8 bfr = *(const short8*)&Bs[jt * 16 + lrow][lk];
                acc1[jt] = __builtin_amdgcn_mfma_f32_16x16x32_bf16(a, bfr, acc1[jt], 0, 0, 0);
            }
            __syncthreads();
        }
        #pragma unroll
        for (int jt = 0; jt < 16; jt++) {
            int col = jt * 16 + lrow;
            float bs = b1m[col];
            #pragma unroll
            for (int r = 0; r < 4; r++) {
                int row = wv * 16 + quad * 4 + r;
                Hs[row][col] = f2b(gelu_f(acc1[jt][r] + bs));
            }
        }
    }
    __syncthreads();

    // ---- GEMM2: out += H @ W2m + b2m, K=256, N=128 ----
    float4v acc2[8] = {};
    #pragma unroll
    for (int kt = 0; kt < 8; kt++) {
        int k0 = kt * 32;
        #pragma unroll
        for (int it = 0; it < 2; it++) {
            int idx = tid + it * 256;
            int n = idx >> 2, part = idx & 3;
            *(uint4*)&Bs[n][part * 8] =
                *(const uint4*)(W2T + (size_t)n * 256 + k0 + part * 8);
        }
        __syncthreads();
        short8 a = *(const short8*)&Hs[wv * 16 + lrow][k0 + lk];
        #pragma unroll
        for (int jt = 0; jt < 8; jt++) {
            short8 bfr = *(const short8*)&Bs[jt * 16 + lrow][lk];
            acc2[jt] = __builtin_amdgcn_mfma_f32_16x16x32_bf16(a, bfr, acc2[jt], 0, 0, 0);
        }
        __syncthreads();
    }
    #pragma unroll
    for (int jt = 0; jt < 8; jt++) {
        int col = jt * 16 + lrow;
        float bs = b2m[col];
        #pragma unroll
        for (int r = 0; r < 4; r++) {
            int row = m0 + wv * 16 + quad * 4 + r;
            float* p = out + (size_t)row * CC + col;
            *p = *p + acc2[jt][r] + bs;
        }
    }
}

extern "C" void kernel_launch(void* const* d_in, const int* in_sizes, int n_in,
                              void* d_out, int out_size, void* d_ws, size_t ws_size,
                              hipStream_t stream) {
    const float* x      = (const float*)d_in[0];
    const float* g1     = (const float*)d_in[1];
    const float* b1     = (const float*)d_in[2];
    const float* W_in   = (const float*)d_in[3];
    const float* conv_w = (const float*)d_in[4];
    const float* conv_b = (const float*)d_in[5];
    const float* Wx     = (const float*)d_in[6];
    const float* Wdt    = (const float*)d_in[7];
    const float* bdt    = (const float*)d_in[8];
    const float* A_log  = (const float*)d_in[9];
    const float* Dvec   = (const float*)d_in[10];
    const float* conv_wb= (const float*)d_in[11];
    const float* conv_bb= (const float*)d_in[12];
    const float* Wxb    = (const float*)d_in[13];
    const float* Wdtb   = (const float*)d_in[14];
    const float* bdtb   = (const float*)d_in[15];
    const float* A_b_log= (const float*)d_in[16];
    const float* D_b    = (const float*)d_in[17];
    const float* W_out  = (const float*)d_in[18];
    const float* g2     = (const float*)d_in[19];
    const float* b2     = (const float*)d_in[20];
    const float* g3     = (const float*)d_in[21];
    const float* b3     = (const float*)d_in[22];
    const float* W1m    = (const float*)d_in[23];
    const float* b1m    = (const float*)d_in[24];
    const float* W2m    = (const float*)d_in[25];
    const float* b2m    = (const float*)d_in[26];

    // Workspace: 128 MiB of bf16 intermediates.
    bf16* ws  = (bf16*)d_ws;
    bf16* XZ  = ws;                    // [ROWS][512] bf16 = 64 MiB  [0, 64M)
    bf16* YF  = ws + 33554432UL;       // [ROWS][256] bf16 = 32 MiB  (u_f then y_f)
    bf16* YB  = ws + 50331648UL;       // [ROWS][256] bf16 = 32 MiB  (u_b then y_b)
    float* out = (float*)d_out;        // 8,388,608 fp32 = 32 MiB
    // d_out as scratch (dead before the real fp32 write of d_out):
    bf16* XDBL_F = (bf16*)d_out;       // [ROWS][40] bf16 = 5.24 MiB
    bf16* XDBL_B = (bf16*)d_out + 2621440UL;   // ends at 10.5 MiB
    // XZ is dead after ln2res -> reuse its head for pre-transposed weights:
    bf16* W1T = XZ;                    // [256][128] bf16 = 64 KiB
    bf16* W2T = XZ + 32768UL;          // [128][256] bf16 = 64 KiB

    // 1+2 fused: XZ = LN1(x) @ W_in.T  [65536 x 512]  (MFMA, A staged once)
    ln1_win_kernel<<<ROWS / 64, 256, 0, stream>>>(x, g1, b1, W_in, XZ);
    // 3. xdbl (fwd/bwd): MFMA GEMM with fused conv+SiLU A-staging; u tiles -> YF/YB
    mfma_conv_kernel<0><<<SSEQ * 4, 256, 0, stream>>>(XZ, conv_w, conv_b, Wx, XDBL_F, YF);
    mfma_conv_kernel<1><<<SSEQ * 4, 256, 0, stream>>>(XZ, conv_wb, conv_bb, Wxb, XDBL_B, YB);
    // 4. scan (v5 structure + LDS u staging): reads u from YF/YB, overwrites with y
    scan_kernel<<<512, 256, 0, stream>>>(XDBL_F, XDBL_B,
        Wdt, bdt, A_log, Dvec, Wdtb, bdtb, A_b_log, D_b, YF, YB);
    // 5. yproj = ((YF+YB)*silu(z)) @ W_out.T, fused LN2 + residual -> d_out fp32 (MFMA)
    mfma_ln2res_kernel<<<ROWS / 64, 256, 0, stream>>>(YF, YB, XZ, W_out, g2, b2, x, out);
    // 5b. pre-transpose MLP weights into dead XZ region (bf16, n-major)
    prep_w_kernel<<<128, 256, 0, stream>>>(W1m, W2m, W1T, W2T);
    // 6-8 fused: d_out += gelu(LN3(d_out) @ W1m + b1m) @ W2m + b2m
    mlp_fused_kernel<<<ROWS / 64, 256, 0, stream>>>(out, g3, b3, W1T, b1m, W2T, b2m);
}

// Round 12
// 452.073 us; speedup vs baseline: 1.0443x; 1.0443x over previous
//
#include <hip/hip_runtime.h>
#include <hip/hip_bf16.h>
#include <math.h>

// Problem dims
#define CC 128          // C
#define DI 256          // D_INNER
#define SSEQ 256        // B*N sequences
#define ROWS 65536      // SSEQ*TT

typedef __hip_bfloat16 bf16;
typedef __attribute__((ext_vector_type(8))) short short8;   // 8 bf16 (4 VGPRs) MFMA A/B frag
typedef __attribute__((ext_vector_type(4))) float float4v;  // MFMA C/D frag
typedef __attribute__((ext_vector_type(2))) float f32x2;    // packed fp32 (v_pk_*)

__device__ __forceinline__ float to_f(float v) { return v; }
__device__ __forceinline__ float to_f(bf16 v)  { return __bfloat162float(v); }
__device__ __forceinline__ bf16  f2b(float v)  { return __float2bfloat16(v); }
__device__ __forceinline__ float bf2f_bits(short v) {
    union { unsigned u; float f; } c; c.u = ((unsigned)(unsigned short)v) << 16; return c.f;
}
__device__ __forceinline__ f32x2 mk2(float a, float b) { f32x2 r; r.x = a; r.y = b; return r; }
__device__ __forceinline__ f32x2 fma2(f32x2 a, f32x2 b, f32x2 c) { return a * b + c; }

__device__ __forceinline__ float wave_sum(float v) {
    #pragma unroll
    for (int o = 1; o < 64; o <<= 1) v += __shfl_xor(v, o, 64);
    return v;
}
__device__ __forceinline__ float silu_f(float x) {
    return x * __builtin_amdgcn_rcpf(1.f + __expf(-x));
}
__device__ __forceinline__ float gelu_f(float x) { return 0.5f * x * (1.f + erff(x * 0.70710678118654752f)); }
__device__ __forceinline__ float softplus_f(float x) {
    return (x > 20.f) ? x : __logf(1.f + __expf(x));
}

// ---------------- LN1: x (B,T,N,C) fp32 -> bf16 rows in (s,t) order, s = b*64+n ----------------
__global__ __launch_bounds__(256) void ln1_kernel(const float* __restrict__ x,
                                                  const float* __restrict__ g,
                                                  const float* __restrict__ b,
                                                  bf16* __restrict__ out) {
    int wave = threadIdx.x >> 6, lane = threadIdx.x & 63;
    int r = blockIdx.x * 4 + wave;
    int s = r >> 8, t = r & 255;
    int bb = s >> 6, n = s & 63;
    size_t xbase = (((size_t)(bb * 256 + t)) * 64 + n) * CC;
    float v0 = x[xbase + lane], v1 = x[xbase + lane + 64];
    float s1 = wave_sum(v0 + v1);
    float s2 = wave_sum(v0 * v0 + v1 * v1);
    float m = s1 * (1.f / 128.f);
    float var = s2 * (1.f / 128.f) - m * m;
    float rstd = rsqrtf(var + 1e-5f);
    size_t ob = (size_t)r * CC;
    out[ob + lane]      = f2b((v0 - m) * rstd * g[lane]      + b[lane]);
    out[ob + lane + 64] = f2b((v1 - m) * rstd * g[lane + 64] + b[lane + 64]);
}

// ---------------- prep0: cast W_in / Wx / Wxb to bf16 once (layout unchanged) ----------------
// Removes ~67M per-block f2b ops from the W_in GEMM B-staging (8192 blocks x
// 8192 elems) and ~8M from the conv kernels; halves their B fetch bytes.
__global__ __launch_bounds__(256) void prep0_kernel(const float* __restrict__ Win,
                                                    const float* __restrict__ Wx,
                                                    const float* __restrict__ Wxb,
                                                    bf16* __restrict__ WinT,
                                                    bf16* __restrict__ WxT,
                                                    bf16* __restrict__ WxbT) {
    int e = blockIdx.x * 256 + threadIdx.x;   // grid 256 -> e in [0, 65536)
    WinT[e] = f2b(Win[e]);                    // [512][128], dtype cast only
    if (e < 40 * 256) { WxT[e] = f2b(Wx[e]); WxbT[e] = f2b(Wxb[e]); }
}

// ======== W_in GEMM, 64x64 tile, 256 threads — bf16 pre-cast B (no per-block f2b) ========
__global__ __launch_bounds__(256) void win_gemm_kernel(const bf16* __restrict__ A,    // [ROWS][128]
                                                       const bf16* __restrict__ BT,   // [512][128] bf16
                                                       bf16* __restrict__ C) {        // [ROWS][512]
    __shared__ bf16 As[64][40];
    __shared__ bf16 Bs[64][40];
    int tid = threadIdx.x;
    int m0 = blockIdx.x * 64;
    int n0 = blockIdx.y * 64;
    int wv = tid >> 6, lane = tid & 63;
    int lrow = lane & 15, quad = lane >> 4;
    int lk = quad * 8;
    float4v acc[4] = {};
    #pragma unroll
    for (int kt = 0; kt < 4; kt++) {
        int k0 = kt * 32;
        {
            int m = tid >> 2, part = tid & 3;
            *(uint4*)&As[m][part * 8] = *(const uint4*)(A  + (size_t)(m0 + m) * 128 + k0 + part * 8);
            *(uint4*)&Bs[m][part * 8] = *(const uint4*)(BT + (size_t)(n0 + m) * 128 + k0 + part * 8);
        }
        __syncthreads();
        short8 a = *(const short8*)&As[wv * 16 + lrow][lk];
        #pragma unroll
        for (int jt = 0; jt < 4; jt++) {
            short8 bfr = *(const short8*)&Bs[jt * 16 + lrow][lk];
            acc[jt] = __builtin_amdgcn_mfma_f32_16x16x32_bf16(a, bfr, acc[jt], 0, 0, 0);
        }
        __syncthreads();
    }
    #pragma unroll
    for (int jt = 0; jt < 4; jt++) {
        int col = n0 + jt * 16 + lrow;
        #pragma unroll
        for (int r = 0; r < 4; r++) {
            int row = m0 + wv * 16 + quad * 4 + r;
            C[(size_t)row * 512 + col] = f2b(acc[jt][r]);
        }
    }
}

// ======== MFMA W_out GEMM (64x128 tile), A = (YF+YB)*silu(z), fused LN2 + residual ========
__global__ __launch_bounds__(256) void mfma_ln2res_kernel(const bf16* __restrict__ YF,
                                                          const bf16* __restrict__ YB,
                                                          const bf16* __restrict__ xz,
                                                          const float* __restrict__ Wout,
                                                          const float* __restrict__ g,
                                                          const float* __restrict__ b,
                                                          const float* __restrict__ x,
                                                          float* __restrict__ out) {
    __shared__ bf16 As[64][40];
    __shared__ bf16 Bs[128][40];
    int tid = threadIdx.x;
    int m0 = blockIdx.x * 64;
    int wv = tid >> 6, lane = tid & 63;
    int lrow = lane & 15, quad = lane >> 4;
    int lk = quad * 8;
    float4v acc[8] = {};
    #pragma unroll
    for (int kt = 0; kt < 8; kt++) {          // K = 256
        int k0 = kt * 32;
        {
            int m = tid >> 2, part = tid & 3;
            size_t off = (size_t)(m0 + m) * 256 + k0 + part * 8;
            short8 vf = *(const short8*)(YF + off);
            short8 vb = *(const short8*)(YB + off);
            short8 vz = *(const short8*)(xz + (size_t)(m0 + m) * 512 + 256 + k0 + part * 8);
            bf16 tmp[8];
            #pragma unroll
            for (int j = 0; j < 8; j++)
                tmp[j] = f2b((bf2f_bits(vf[j]) + bf2f_bits(vb[j])) * silu_f(bf2f_bits(vz[j])));
            *(uint4*)&As[m][part * 8] = *(uint4*)tmp;
        }
        #pragma unroll
        for (int it = 0; it < 2; it++) {
            int idx = tid + it * 256;
            int n = idx >> 2, part = idx & 3;
            const float* src = Wout + (size_t)n * 256 + k0 + part * 8;
            bf16 tmp[8];
            #pragma unroll
            for (int j = 0; j < 8; j++) tmp[j] = f2b(src[j]);
            *(uint4*)&Bs[n][part * 8] = *(uint4*)tmp;
        }
        __syncthreads();
        short8 a = *(const short8*)&As[wv * 16 + lrow][lk];
        #pragma unroll
        for (int jt = 0; jt < 8; jt++) {
            short8 bfr = *(const short8*)&Bs[jt * 16 + lrow][lk];
            acc[jt] = __builtin_amdgcn_mfma_f32_16x16x32_bf16(a, bfr, acc[jt], 0, 0, 0);
        }
        __syncthreads();
    }
    #pragma unroll
    for (int r = 0; r < 4; r++) {
        float ps = 0.f, ps2 = 0.f;
        #pragma unroll
        for (int jt = 0; jt < 8; jt++) { float v = acc[jt][r]; ps += v; ps2 += v * v; }
        #pragma unroll
        for (int o = 1; o < 16; o <<= 1) {
            ps  += __shfl_xor(ps, o, 64);
            ps2 += __shfl_xor(ps2, o, 64);
        }
        float m = ps * (1.f / 128.f);
        float var = ps2 * (1.f / 128.f) - m * m;
        float rstd = rsqrtf(var + 1e-5f);
        int row = m0 + wv * 16 + quad * 4 + r;
        int s = row >> 8, t = row & 255;
        int bb = s >> 6, n = s & 63;
        size_t xbase = (((size_t)(bb * 256 + t)) * 64 + n) * CC;
        #pragma unroll
        for (int jt = 0; jt < 8; jt++) {
            int col = jt * 16 + lrow;
            out[xbase + col] = (acc[jt][r] - m) * rstd * g[col] + b[col] + x[xbase + col];
        }
    }
}

// ======== MFMA xdbl GEMM with fused causal conv + SiLU A-staging (bf16 Wx) ========
template <int DIR>
__global__ __launch_bounds__(256) void mfma_conv_kernel(const bf16* __restrict__ xz,
                                                        const float* __restrict__ cw,
                                                        const float* __restrict__ cb,
                                                        const bf16* __restrict__ WxT,
                                                        bf16* __restrict__ C,
                                                        bf16* __restrict__ U) {
    __shared__ bf16 As[64][40];
    __shared__ bf16 Bs[48][40];
    int tid = threadIdx.x;
    int s = blockIdx.x >> 2;
    int t0 = (blockIdx.x & 3) * 64;
    int wv = tid >> 6, lane = tid & 63;
    int lrow = lane & 15, quad = lane >> 4;
    int lk = quad * 8;
    float4v acc[3] = {};
    #pragma unroll
    for (int kt = 0; kt < 8; kt++) {          // K = 256 channels
        int k0 = kt * 32;
        {
            int m = tid >> 2, part = tid & 3;
            int t = t0 + m;
            int dbase = k0 + part * 8;
            float a[8];
            float4 w4[8];
            #pragma unroll
            for (int i = 0; i < 8; i++) {
                a[i]  = cb[dbase + i];
                w4[i] = ((const float4*)cw)[dbase + i];   // cw[d][0..3]
            }
            #pragma unroll
            for (int j = 0; j < 4; j++) {
                int tj = t - 3 + j;
                if (tj >= 0) {
                    int src = DIR ? (255 - tj) : tj;
                    uint4 v = *(const uint4*)(xz + (size_t)(s * 256 + src) * 512 + dbase);
                    short8 sv = *(short8*)&v;
                    #pragma unroll
                    for (int i = 0; i < 8; i++) {
                        float w = (j == 0) ? w4[i].x : (j == 1) ? w4[i].y : (j == 2) ? w4[i].z : w4[i].w;
                        a[i] += w * bf2f_bits(sv[i]);
                    }
                }
            }
            bf16 tmp[8];
            #pragma unroll
            for (int i = 0; i < 8; i++) tmp[i] = f2b(silu_f(a[i]));
            *(uint4*)&As[m][part * 8] = *(uint4*)tmp;
            int tu = DIR ? (255 - t) : t;
            *(uint4*)&U[((size_t)(s * 256 + tu)) * 256 + dbase] = *(uint4*)tmp;
        }
        {
            int n = tid >> 2, part = tid & 3;
            if (n < 48) {
                if (n < 40) {
                    *(uint4*)&Bs[n][part * 8] =
                        *(const uint4*)(WxT + (size_t)n * 256 + k0 + part * 8);
                } else {
                    uint4 z = {0u, 0u, 0u, 0u};
                    *(uint4*)&Bs[n][part * 8] = z;
                }
            }
        }
        __syncthreads();
        short8 a = *(const short8*)&As[wv * 16 + lrow][lk];
        #pragma unroll
        for (int jt = 0; jt < 3; jt++) {
            short8 bfr = *(const short8*)&Bs[jt * 16 + lrow][lk];
            acc[jt] = __builtin_amdgcn_mfma_f32_16x16x32_bf16(a, bfr, acc[jt], 0, 0, 0);
        }
        __syncthreads();
    }
    #pragma unroll
    for (int jt = 0; jt < 3; jt++) {
        int col = jt * 16 + lrow;
        if (col < 40) {
            #pragma unroll
            for (int r = 0; r < 4; r++) {
                int row = t0 + wv * 16 + quad * 4 + r;
                C[(size_t)(s * 256 + row) * 40 + col] = f2b(acc[jt][r]);
            }
        }
    }
}

// ---------------- Selective scan v10 (unchanged from R8: 102us) ----------------

#define LOADROW(R, T) do {                                                  \
    const float4* rp_ = (const float4*)(rows + (T) * 40);                   \
    R##0 = rp_[0]; R##1 = rp_[1]; R##2 = rp_[2]; R##3 = rp_[3];             \
    R##4 = rp_[4]; R##5 = rp_[5]; R##6 = rp_[6]; R##7 = rp_[7];             \
    R##8 = rp_[8]; R##9 = rp_[9];                                           \
} while (0)

#define SCAN_STEP(JJ, R) do {                                               \
    float u_ = to_f(ub[(JJ) * 256 + d]);                                    \
    f32x2 acc2 = mk2((R##0).x, (R##0).y) * wdt01;                           \
    acc2 = fma2(mk2((R##0).z, (R##0).w), wdt23, acc2);                      \
    acc2 = fma2(mk2((R##1).x, (R##1).y), wdt45, acc2);                      \
    acc2 = fma2(mk2((R##1).z, (R##1).w), wdt67, acc2);                      \
    float dtr_ = bd + acc2.x + acc2.y;                                      \
    float dt_ = softplus_f(dtr_);                                           \
    float du_ = dt_ * u_;                                                   \
    float d1 = __expf(dt_ * A0);                                            \
    float d2v = d1 * d1;                                                    \
    f32x2 pw0 = mk2(d1, d2v);                                               \
    f32x2 dd2 = mk2(d2v, d2v);                                              \
    f32x2 pw1 = pw0 * dd2, pw2 = pw1 * dd2, pw3 = pw2 * dd2;                \
    f32x2 dd8 = mk2(pw3.y, pw3.y);                                          \
    f32x2 pw4 = pw0 * dd8, pw5 = pw1 * dd8, pw6 = pw2 * dd8, pw7 = pw3 * dd8; \
    f32x2 du2 = mk2(du_, du_);                                              \
    hp0 = fma2(pw0, hp0, du2 * mk2((R##2).x, (R##2).y));                    \
    hp1 = fma2(pw1, hp1, du2 * mk2((R##2).z, (R##2).w));                    \
    hp2 = fma2(pw2, hp2, du2 * mk2((R##3).x, (R##3).y));                    \
    hp3 = fma2(pw3, hp3, du2 * mk2((R##3).z, (R##3).w));                    \
    hp4 = fma2(pw4, hp4, du2 * mk2((R##4).x, (R##4).y));                    \
    hp5 = fma2(pw5, hp5, du2 * mk2((R##4).z, (R##4).w));                    \
    hp6 = fma2(pw6, hp6, du2 * mk2((R##5).x, (R##5).y));                    \
    hp7 = fma2(pw7, hp7, du2 * mk2((R##5).z, (R##5).w));                    \
    f32x2 ya = hp0 * mk2((R##6).x, (R##6).y);                               \
    f32x2 yb2 = hp1 * mk2((R##6).z, (R##6).w);                              \
    ya = fma2(hp2, mk2((R##7).x, (R##7).y), ya);                            \
    yb2 = fma2(hp3, mk2((R##7).z, (R##7).w), yb2);                          \
    ya = fma2(hp4, mk2((R##8).x, (R##8).y), ya);                            \
    yb2 = fma2(hp5, mk2((R##8).z, (R##8).w), yb2);                          \
    ya = fma2(hp6, mk2((R##9).x, (R##9).y), ya);                            \
    yb2 = fma2(hp7, mk2((R##9).z, (R##9).w), yb2);                          \
    f32x2 ys = ya + yb2;                                                    \
    float yv_ = ys.x + ys.y + u_ * Dd;                                      \
    *yp = f2b(yv_); yp += ystep;                                            \
} while (0)

// stage one 32-step u chunk (16 KB) into u_lds[buf]; fully coalesced
#define STAGE_U(BUF, C0) do {                                               \
    _Pragma("unroll")                                                       \
    for (int q_ = 0; q_ < 4; q_++) {                                        \
        int flat_ = q_ * 256 + tid;                                         \
        int j_ = flat_ >> 5, w_ = flat_ & 31;                               \
        int t_ = (C0) + j_;                                                 \
        int grow_ = dir ? (255 - t_) : t_;                                  \
        ((uint4*)u_lds)[(BUF) * 1024 + flat_] =                             \
            *((const uint4*)(Y + ((size_t)(s * 256 + grow_)) * 256) + w_);  \
    }                                                                       \
} while (0)

__global__ __launch_bounds__(256, 2) void scan_kernel(
        const bf16* __restrict__ xdbl_f, const bf16* __restrict__ xdbl_b,
        const float* __restrict__ Wdt_f, const float* __restrict__ bdt_f,
        const float* __restrict__ Alog_f, const float* __restrict__ D_f,
        const float* __restrict__ Wdt_b, const float* __restrict__ bdt_b,
        const float* __restrict__ Alog_b, const float* __restrict__ D_b,
        bf16* __restrict__ YF, bf16* __restrict__ YB) {
    __shared__ float rows[256 * 40];     // 40 KB fp32
    __shared__ bf16  u_lds[2 * 8192];    // 32 KB: 2 x (32 steps x 256 ch)
    int tid = threadIdx.x;
    int dir = blockIdx.x >> 8;
    int s = blockIdx.x & 255;
    int d = tid;

    const bf16* xd = (dir ? xdbl_b : xdbl_f) + (size_t)s * 10240;
    #pragma unroll
    for (int i = 0; i < 5; i++) {
        int idx = i * 256 + tid;
        uint4 v = ((const uint4*)xd)[idx];
        short8 sv = *(short8*)&v;
        float f[8];
        #pragma unroll
        for (int j = 0; j < 8; j++) f[j] = bf2f_bits(sv[j]);
        *(float4*)&rows[idx * 8]     = *(float4*)&f[0];
        *(float4*)&rows[idx * 8 + 4] = *(float4*)&f[4];
    }

    const float* Alog = dir ? Alog_b : Alog_f;
    const float* Wdtp = dir ? Wdt_b  : Wdt_f;
    float Aarr[16];
    #pragma unroll
    for (int n = 0; n < 16; n++) Aarr[n] = -__expf(Alog[d * 16 + n]);
    f32x2 wdt01 = mk2(Wdtp[d * 8 + 0], Wdtp[d * 8 + 1]);
    f32x2 wdt23 = mk2(Wdtp[d * 8 + 2], Wdtp[d * 8 + 3]);
    f32x2 wdt45 = mk2(Wdtp[d * 8 + 4], Wdtp[d * 8 + 5]);
    f32x2 wdt67 = mk2(Wdtp[d * 8 + 6], Wdtp[d * 8 + 7]);
    float bd = dir ? bdt_b[d] : bdt_f[d];
    float Dd = dir ? D_b[d]   : D_f[d];
    bf16* Y = dir ? YB : YF;

    // Structure check: A[n] == (n+1)*A[0]
    float A0 = Aarr[0];
    int pw = 1;
    #pragma unroll
    for (int n = 1; n < 16; n++)
        pw &= (fabsf(Aarr[n] - (float)(n + 1) * A0) <= 1e-4f * fabsf(Aarr[n]) + 1e-6f) ? 1 : 0;
    pw = __all(pw);

    // stage u chunk 0
    STAGE_U(0, 0);
    __syncthreads();

    // y pointer walks the same buffer u was staged from (u already in LDS)
    bf16* yp = Y + ((size_t)(s * 256 + (dir ? 255 : 0))) * 256 + d;
    ptrdiff_t ystep = dir ? -256 : 256;

    if (pw) {
        f32x2 hp0 = {}, hp1 = {}, hp2 = {}, hp3 = {},
              hp4 = {}, hp5 = {}, hp6 = {}, hp7 = {};
        float4 ra0, ra1, ra2, ra3, ra4, ra5, ra6, ra7, ra8, ra9;
        float4 rb0, rb1, rb2, rb3, rb4, rb5, rb6, rb7, rb8, rb9;
        LOADROW(ra, 0);
        #pragma unroll 1
        for (int c = 0; c < 8; c++) {
            if (c + 1 < 8) STAGE_U((c + 1) & 1, (c + 1) * 32);
            const bf16* ub = u_lds + (c & 1) * 8192;
            int tc = c * 32;
            #pragma unroll 2
            for (int j = 0; j < 32; j += 2) {
                int t = tc + j;
                LOADROW(rb, t + 1);
                SCAN_STEP(j, ra);
                if (t + 2 < 256) LOADROW(ra, t + 2);
                SCAN_STEP(j + 1, rb);
            }
            __syncthreads();
        }
    } else {
        float h[16];
        #pragma unroll
        for (int n = 0; n < 16; n++) h[n] = 0.f;
        #pragma unroll 1
        for (int c = 0; c < 8; c++) {
            if (c + 1 < 8) STAGE_U((c + 1) & 1, (c + 1) * 32);
            const bf16* ub = u_lds + (c & 1) * 8192;
            int tc = c * 32;
            #pragma unroll 1
            for (int j = 0; j < 32; j++) {
                float u = to_f(ub[j * 256 + d]);
                const float* row = rows + (tc + j) * 40;
                float4 q0 = *(const float4*)(row);
                float4 q1 = *(const float4*)(row + 4);
                float dtr = bd;
                dtr += q0.x * wdt01.x + q0.y * wdt01.y + q0.z * wdt23.x + q0.w * wdt23.y;
                dtr += q1.x * wdt45.x + q1.y * wdt45.y + q1.z * wdt67.x + q1.w * wdt67.y;
                float dt = softplus_f(dtr);
                float du = dt * u, y = 0.f;
                #pragma unroll
                for (int n = 0; n < 16; n++) {
                    float dA = __expf(dt * Aarr[n]);
                    h[n] = dA * h[n] + du * row[8 + n];
                    y += h[n] * row[24 + n];
                }
                y += u * Dd;
                *yp = f2b(y); yp += ystep;
            }
            __syncthreads();
        }
    }
}

// ---------------- Weight pre-transpose: W1m/W2m fp32 k-major -> bf16 n-major ----------------
__global__ __launch_bounds__(256) void prep_w_kernel(const float* __restrict__ W1m,
                                                     const float* __restrict__ W2m,
                                                     bf16* __restrict__ W1T,
                                                     bf16* __restrict__ W2T) {
    int e = blockIdx.x * 256 + threadIdx.x;   // 0..32767
    {   // W1m [128][256] -> W1T [256][128]
        int k = e >> 8, n = e & 255;
        W1T[n * 128 + k] = f2b(W1m[k * 256 + n]);
    }
    {   // W2m [256][128] -> W2T [128][256]
        int k = e >> 7, n = e & 127;
        W2T[n * 256 + k] = f2b(W2m[k * 128 + n]);
    }
}

// ---------------- Fused MLP tail: LN3 + gelu(H@W1m+b1m)@W2m + b2m + residual ----------------
__global__ __launch_bounds__(256) void mlp_fused_kernel(
        float* __restrict__ out,
        const float* __restrict__ g3, const float* __restrict__ b3,
        const bf16* __restrict__ W1T, const float* __restrict__ b1m,
        const bf16* __restrict__ W2T, const float* __restrict__ b2m) {
    __shared__ bf16 As[64][136];   // LN3 rows (272B stride)
    __shared__ bf16 Hs[64][264];   // hidden   (528B stride)
    __shared__ bf16 Bs[256][40];   // weight k-tile (shared by both GEMMs)
    int tid = threadIdx.x;
    int m0 = blockIdx.x * 64;
    int wv = tid >> 6, lane = tid & 63;
    int lrow = lane & 15, quad = lane >> 4;
    int lk = quad * 8;

    // ---- Phase 0: LN3 on 64 rows -> As (bf16) ----
    {
        int m = tid >> 2, part = tid & 3;        // 4 threads/row, 32 floats each
        const float* src = out + (size_t)(m0 + m) * CC + part * 32;
        float v[32];
        #pragma unroll
        for (int i = 0; i < 8; i++) {
            float4 q = ((const float4*)src)[i];
            v[i * 4 + 0] = q.x; v[i * 4 + 1] = q.y;
            v[i * 4 + 2] = q.z; v[i * 4 + 3] = q.w;
        }
        float s1 = 0.f, s2 = 0.f;
        #pragma unroll
        for (int i = 0; i < 32; i++) { s1 += v[i]; s2 += v[i] * v[i]; }
        s1 += __shfl_xor(s1, 1, 64); s2 += __shfl_xor(s2, 1, 64);
        s1 += __shfl_xor(s1, 2, 64); s2 += __shfl_xor(s2, 2, 64);
        float mean = s1 * (1.f / 128.f);
        float var = s2 * (1.f / 128.f) - mean * mean;
        float rstd = rsqrtf(var + 1e-5f);
        #pragma unroll
        for (int i8 = 0; i8 < 4; i8++) {
            bf16 tmp[8];
            #pragma unroll
            for (int j = 0; j < 8; j++) {
                int col = part * 32 + i8 * 8 + j;
                tmp[j] = f2b((v[i8 * 8 + j] - mean) * rstd * g3[col] + b3[col]);
            }
            *(uint4*)&As[m][part * 32 + i8 * 8] = *(uint4*)tmp;
        }
    }
    __syncthreads();

    // ---- GEMM1: H = gelu(LN3 @ W1m + b1m), K=128, N=256 -> Hs ----
    {
        float4v acc1[16] = {};
        #pragma unroll
        for (int kt = 0; kt < 4; kt++) {
            int k0 = kt * 32;
            #pragma unroll
            for (int it = 0; it < 4; it++) {
                int idx = tid + it * 256;
                int n = idx >> 2, part = idx & 3;
                *(uint4*)&Bs[n][part * 8] =
                    *(const uint4*)(W1T + (size_t)n * 128 + k0 + part * 8);
            }
            __syncthreads();
            short8 a = *(const short8*)&As[wv * 16 + lrow][k0 + lk];
            #pragma unroll
            for (int jt = 0; jt < 16; jt++) {
                short8 bfr = *(const short8*)&Bs[jt * 16 + lrow][lk];
                acc1[jt] = __builtin_amdgcn_mfma_f32_16x16x32_bf16(a, bfr, acc1[jt], 0, 0, 0);
            }
            __syncthreads();
        }
        #pragma unroll
        for (int jt = 0; jt < 16; jt++) {
            int col = jt * 16 + lrow;
            float bs = b1m[col];
            #pragma unroll
            for (int r = 0; r < 4; r++) {
                int row = wv * 16 + quad * 4 + r;
                Hs[row][col] = f2b(gelu_f(acc1[jt][r] + bs));
            }
        }
    }
    __syncthreads();

    // ---- GEMM2: out += H @ W2m + b2m, K=256, N=128 ----
    float4v acc2[8] = {};
    #pragma unroll
    for (int kt = 0; kt < 8; kt++) {
        int k0 = kt * 32;
        #pragma unroll
        for (int it = 0; it < 2; it++) {
            int idx = tid + it * 256;
            int n = idx >> 2, part = idx & 3;
            *(uint4*)&Bs[n][part * 8] =
                *(const uint4*)(W2T + (size_t)n * 256 + k0 + part * 8);
        }
        __syncthreads();
        short8 a = *(const short8*)&Hs[wv * 16 + lrow][k0 + lk];
        #pragma unroll
        for (int jt = 0; jt < 8; jt++) {
            short8 bfr = *(const short8*)&Bs[jt * 16 + lrow][lk];
            acc2[jt] = __builtin_amdgcn_mfma_f32_16x16x32_bf16(a, bfr, acc2[jt], 0, 0, 0);
        }
        __syncthreads();
    }
    #pragma unroll
    for (int jt = 0; jt < 8; jt++) {
        int col = jt * 16 + lrow;
        float bs = b2m[col];
        #pragma unroll
        for (int r = 0; r < 4; r++) {
            int row = m0 + wv * 16 + quad * 4 + r;
            float* p = out + (size_t)row * CC + col;
            *p = *p + acc2[jt][r] + bs;
        }
    }
}

extern "C" void kernel_launch(void* const* d_in, const int* in_sizes, int n_in,
                              void* d_out, int out_size, void* d_ws, size_t ws_size,
                              hipStream_t stream) {
    const float* x      = (const float*)d_in[0];
    const float* g1     = (const float*)d_in[1];
    const float* b1     = (const float*)d_in[2];
    const float* W_in   = (const float*)d_in[3];
    const float* conv_w = (const float*)d_in[4];
    const float* conv_b = (const float*)d_in[5];
    const float* Wx     = (const float*)d_in[6];
    const float* Wdt    = (const float*)d_in[7];
    const float* bdt    = (const float*)d_in[8];
    const float* A_log  = (const float*)d_in[9];
    const float* Dvec   = (const float*)d_in[10];
    const float* conv_wb= (const float*)d_in[11];
    const float* conv_bb= (const float*)d_in[12];
    const float* Wxb    = (const float*)d_in[13];
    const float* Wdtb   = (const float*)d_in[14];
    const float* bdtb   = (const float*)d_in[15];
    const float* A_b_log= (const float*)d_in[16];
    const float* D_b    = (const float*)d_in[17];
    const float* W_out  = (const float*)d_in[18];
    const float* g2     = (const float*)d_in[19];
    const float* b2     = (const float*)d_in[20];
    const float* g3     = (const float*)d_in[21];
    const float* b3     = (const float*)d_in[22];
    const float* W1m    = (const float*)d_in[23];
    const float* b1m    = (const float*)d_in[24];
    const float* W2m    = (const float*)d_in[25];
    const float* b2m    = (const float*)d_in[26];

    // Workspace: 128 MiB of bf16 intermediates.
    bf16* ws  = (bf16*)d_ws;
    bf16* XZ  = ws;                    // [ROWS][512] bf16 = 64 MiB  [0, 64M)
    bf16* YF  = ws + 33554432UL;       // [ROWS][256] bf16 = 32 MiB  (u_f then y_f)
    bf16* YB  = ws + 50331648UL;       // [ROWS][256] bf16 = 32 MiB  (u_b then y_b)
    float* out = (float*)d_out;        // 8,388,608 fp32 = 32 MiB
    // d_out as scratch (dead before the real fp32 write of d_out):
    bf16* LN1OUT = (bf16*)d_out;       // [ROWS][128] bf16, elements [0, 8388608)
    bf16* XDBL_F = (bf16*)d_out;       // [ROWS][40] bf16, elements [0, 2621440)
    bf16* XDBL_B = (bf16*)d_out + 2621440UL;   // elements [2621440, 5242880)
    // d_out tail (elements [8388608, 16777216)) free until ln2res writes out:
    bf16* WINT = (bf16*)d_out + 8388608UL;     // [512][128] bf16, 65536 els
    bf16* WXT  = (bf16*)d_out + 8454144UL;     // [40][256] bf16, 10240 els
    bf16* WXBT = (bf16*)d_out + 8464384UL;     // [40][256] bf16, 10240 els
    // XZ is dead after ln2res -> reuse its head for pre-transposed MLP weights:
    bf16* W1T = XZ;                    // [256][128] bf16 = 64 KiB
    bf16* W2T = XZ + 32768UL;          // [128][256] bf16 = 64 KiB

    // 0. cast W_in/Wx/Wxb to bf16 once
    prep0_kernel<<<256, 256, 0, stream>>>(W_in, Wx, Wxb, WINT, WXT, WXBT);
    // 1. LN1 -> d_out scratch (bf16)
    ln1_kernel<<<ROWS / 4, 256, 0, stream>>>(x, g1, b1, LN1OUT);
    // 2. XZ = LN1OUT @ W_in.T  [65536 x 512]  (MFMA, bf16 B, 8192 blocks)
    win_gemm_kernel<<<dim3(ROWS / 64, 8), 256, 0, stream>>>(LN1OUT, WINT, XZ);
    // 3. xdbl (fwd/bwd): MFMA GEMM with fused conv+SiLU A-staging; u tiles -> YF/YB
    mfma_conv_kernel<0><<<SSEQ * 4, 256, 0, stream>>>(XZ, conv_w, conv_b, WXT, XDBL_F, YF);
    mfma_conv_kernel<1><<<SSEQ * 4, 256, 0, stream>>>(XZ, conv_wb, conv_bb, WXBT, XDBL_B, YB);
    // 4. scan (v5 structure + LDS u staging): reads u from YF/YB, overwrites with y
    scan_kernel<<<512, 256, 0, stream>>>(XDBL_F, XDBL_B,
        Wdt, bdt, A_log, Dvec, Wdtb, bdtb, A_b_log, D_b, YF, YB);
    // 5. yproj = ((YF+YB)*silu(z)) @ W_out.T, fused LN2 + residual -> d_out fp32 (MFMA)
    mfma_ln2res_kernel<<<ROWS / 64, 256, 0, stream>>>(YF, YB, XZ, W_out, g2, b2, x, out);
    // 5b. pre-transpose MLP weights into dead XZ region (bf16, n-major)
    prep_w_kernel<<<128, 256, 0, stream>>>(W1m, W2m, W1T, W2T);
    // 6-8 fused: d_out += gelu(LN3(d_out) @ W1m + b1m) @ W2m + b2m
    mlp_fused_kernel<<<ROWS / 64, 256, 0, stream>>>(out, g3, b3, W1T, b1m, W2T, b2m);
}